// Round 15
// baseline (289.038 us; speedup 1.0000x reference)
//
#include <hip/hip_runtime.h>
#include <stdint.h>

typedef __bf16 bf16;
typedef __bf16 bf16x4 __attribute__((ext_vector_type(4)));
typedef __bf16 bf16x8 __attribute__((ext_vector_type(8)));
typedef float  f32x4  __attribute__((ext_vector_type(4)));

#define DMODEL 2048
#define NH 16
#define DK 128
#define SS 1024
#define PASTLEN 3072
#define LTOT 4096
#define KVTILES 64
#define NT 64            // kv tiles (no split)

// ---- async global->LDS, 16B per lane (wave-uniform LDS base + lane*16) ----
__device__ __forceinline__ void gload16(const void* g, void* l) {
    __builtin_amdgcn_global_load_lds(
        (__attribute__((address_space(1))) void*)(uintptr_t)g,
        (__attribute__((address_space(3))) void*)(uintptr_t)l,
        16, 0, 0);
}

// ---- fp32 -> bf16 convert, 5 equal-size tensors selected by blockIdx.y ----
__global__ __launch_bounds__(256) void cvt5_k(
    const float* __restrict__ s0, const float* __restrict__ s1,
    const float* __restrict__ s2, const float* __restrict__ s3,
    const float* __restrict__ s4,
    bf16* __restrict__ d0, bf16* __restrict__ d1, bf16* __restrict__ d2,
    bf16* __restrict__ d3, bf16* __restrict__ d4, int n8)
{
    const float* s; bf16* d;
    switch (blockIdx.y) {
        case 0: s = s0; d = d0; break;
        case 1: s = s1; d = d1; break;
        case 2: s = s2; d = d2; break;
        case 3: s = s3; d = d3; break;
        default: s = s4; d = d4; break;
    }
    int stride = gridDim.x * blockDim.x;
    for (int i = blockIdx.x*blockDim.x + threadIdx.x; i < n8; i += stride) {
        const float4* p = (const float4*)s + (size_t)i*2;
        float4 a = p[0], b = p[1];
        bf16x8 o;
        o[0]=(bf16)a.x; o[1]=(bf16)a.y; o[2]=(bf16)a.z; o[3]=(bf16)a.w;
        o[4]=(bf16)b.x; o[5]=(bf16)b.y; o[6]=(bf16)b.z; o[7]=(bf16)b.w;
        *((bf16x8*)d + i) = o;
    }
}

// ---- Y = A(bf16 MxK) @ W^T + bias ; 128x128 tile, BK=32 (m97 structure) ----
__global__ __launch_bounds__(256) void gemm_bt(
    const bf16* __restrict__ A,
    const bf16* __restrict__ W0, const bf16* __restrict__ W1, const bf16* __restrict__ W2,
    const float* __restrict__ b0, const float* __restrict__ b1, const float* __restrict__ b2,
    bf16* __restrict__ outQ, float* __restrict__ outK, float* __restrict__ outV,
    float* __restrict__ outO, int mode)
{
    __shared__ __align__(16) bf16 As[128*32];
    __shared__ __align__(16) bf16 Bs[128*32];
    const int tid  = threadIdx.x;
    const int wave = tid >> 6, lane = tid & 63;
    const int l15 = lane & 15, l4 = lane >> 4;
    int which, ntile;
    if (mode == 0) { which = blockIdx.y >> 4; ntile = blockIdx.y & 15; }
    else           { which = 3;               ntile = blockIdx.y; }
    const bf16*  W    = (mode != 0 || which == 0) ? W0 : (which == 1 ? W1 : W2);
    const float* bias = (mode != 0 || which == 0) ? b0 : (which == 1 ? b1 : b2);
    const int m0 = blockIdx.x * 128, n0 = ntile * 128;
    const int wm = wave >> 1, wn = wave & 1;

    f32x4 acc[4][4] = {};

    for (int k0 = 0; k0 < DMODEL; k0 += 32) {
        __syncthreads();
        #pragma unroll
        for (int c = 0; c < 2; ++c) {
            const int base = c*4096 + wave*1024;
            const int byte = base + lane*16;
            const int row  = byte >> 6;
            const int ke   = (byte & 63) >> 1;
            gload16(A + (size_t)(m0+row)*DMODEL + k0 + ke, (char*)As + base);
            gload16(W + (size_t)(n0+row)*DMODEL + k0 + ke, (char*)Bs + base);
        }
        asm volatile("s_waitcnt vmcnt(0)" ::: "memory");
        __syncthreads();
        bf16x8 af[4], bfv[4];
        #pragma unroll
        for (int mf = 0; mf < 4; ++mf)
            af[mf] = *(const bf16x8*)((const char*)As + (wm*64 + mf*16 + l15)*64 + l4*16);
        #pragma unroll
        for (int nf = 0; nf < 4; ++nf)
            bfv[nf] = *(const bf16x8*)((const char*)Bs + (wn*64 + nf*16 + l15)*64 + l4*16);
        #pragma unroll
        for (int mf = 0; mf < 4; ++mf)
            #pragma unroll
            for (int nf = 0; nf < 4; ++nf)
                acc[mf][nf] = __builtin_amdgcn_mfma_f32_16x16x32_bf16(af[mf], bfv[nf], acc[mf][nf], 0, 0, 0);
    }

    float bv4[4];
    #pragma unroll
    for (int nf = 0; nf < 4; ++nf) bv4[nf] = bias[n0 + wn*64 + nf*16 + l15];

    const int rbase = m0 + wm*64 + l4*4;
    const int cbase = n0 + wn*64 + l15;

    if (mode == 1) {
        #pragma unroll
        for (int mf = 0; mf < 4; ++mf)
        #pragma unroll
        for (int nf = 0; nf < 4; ++nf) {
            const int col = cbase + nf*16;
            #pragma unroll
            for (int r = 0; r < 4; ++r) {
                const int row = rbase + mf*16 + r;
                outO[(size_t)row*DMODEL + col] = acc[mf][nf][r] + bv4[nf];
            }
        }
    } else if (which == 0) {
        const float qs = 0.08838834764831845f * 1.4426950408889634f;
        #pragma unroll
        for (int mf = 0; mf < 4; ++mf)
        #pragma unroll
        for (int nf = 0; nf < 4; ++nf) {
            const int col = cbase + nf*16;
            const int h = col >> 7, d = col & 127;
            #pragma unroll
            for (int r = 0; r < 4; ++r) {
                const int row = rbase + mf*16 + r;
                const int b = row >> 10, s = row & 1023;
                outQ[((size_t)(b*NH + h)*SS + s)*DK + d] = (bf16)((acc[mf][nf][r] + bv4[nf]) * qs);
            }
        }
    } else {
        float* dst = (which == 1) ? outK : outV;
        #pragma unroll
        for (int mf = 0; mf < 4; ++mf)
        #pragma unroll
        for (int nf = 0; nf < 4; ++nf) {
            const int col = cbase + nf*16;
            const int h = col >> 7, d = col & 127;
            #pragma unroll
            for (int r = 0; r < 4; ++r) {
                const int row = rbase + mf*16 + r;
                const int b = row >> 10, s = row & 1023;
                dst[((size_t)(b*NH + h)*LTOT + PASTLEN + s)*DK + d] = acc[mf][nf][r] + bv4[nf];
            }
        }
    }
}

// ---- K/V prep: past fp32 copy to d_out + bf16 swizzled tile blobs for attn ----
// K blob byte(r,d)  = r*256 + ((d*2) ^ ((r&7)<<4))      [64 rows x 128 d]
// V blob: transposed [d][slot], slot j holds original kv row
//   kv(j) = (j&32) + ((j&4)<<2) + (((j>>3)&3)<<2) + (j&3)
// byte(d, j) = d*128 + ((j*2) ^ ((d&7)<<4))
__global__ __launch_bounds__(256) void kvprep_k(
    const float* __restrict__ pk, const float* __restrict__ pv,
    float* __restrict__ Kf, float* __restrict__ Vf,
    bf16* __restrict__ Kb, bf16* __restrict__ Vb)
{
    __shared__ float Vt_f[64*132];
    const int tid = threadIdx.x;
    const int tau = blockIdx.x, bh = blockIdx.y;
    const bool past = tau < 48;
    const size_t srcoff = past ? ((size_t)bh*PASTLEN + tau*64)*DK
                               : ((size_t)bh*LTOT    + tau*64)*DK;
    const float* srcK = (past ? pk : Kf) + srcoff;
    const float* srcV = (past ? pv : Vf) + srcoff;
    float* dstKf = Kf + ((size_t)bh*LTOT + tau*64)*DK;
    float* dstVf = Vf + ((size_t)bh*LTOT + tau*64)*DK;
    char* kblob = (char*)Kb + (((size_t)bh*KVTILES + tau) << 14);
    char* vblob = (char*)Vb + (((size_t)bh*KVTILES + tau) << 14);

    #pragma unroll
    for (int i = 0; i < 8; ++i) {
        const int f4 = i*256 + tid;
        const int r  = f4 >> 5;
        const int c8 = f4 & 31;
        float4 k4 = ((const float4*)srcK)[f4];
        float4 v4 = ((const float4*)srcV)[f4];
        if (past) {
            ((float4*)dstKf)[f4] = k4;
            ((float4*)dstVf)[f4] = v4;
        }
        bf16x4 kq; kq[0]=(bf16)k4.x; kq[1]=(bf16)k4.y; kq[2]=(bf16)k4.z; kq[3]=(bf16)k4.w;
        *(bf16x4*)(kblob + r*256 + ((c8*8) ^ ((r&7)<<4))) = kq;
        *(float4*)&Vt_f[r*132 + c8*4] = v4;
    }
    __syncthreads();
    const int d = tid >> 1, half = tid & 1;
    const int dx = (d & 7) << 4;
    #pragma unroll
    for (int jj = 0; jj < 4; ++jj) {
        const int chunk = half*4 + jj;     // 16B chunk = slots chunk*8 .. +7
        bf16x8 o;
        #pragma unroll
        for (int e = 0; e < 8; ++e) {
            const int j  = chunk*8 + e;
            const int oe = (j & 32) + ((j & 4) << 2) + (((j >> 3) & 3) << 2) + (j & 3);
            o[e] = (bf16)Vt_f[oe*132 + d];
        }
        *(bf16x8*)(vblob + d*128 + ((chunk*16) ^ dx)) = o;
    }
}

// ---- flash attention v14: NO split. 8 waves x 16q, 64 kv tiles, depth-4 ----
// Writes final normalized O directly (no combine pass). Static buffer indices,
// 1 barrier/tile, swapped QK^T (S^T), P fully in-register. Grid 256 = 1/CU.
__global__ __launch_bounds__(512, 2) void attn_k(
    const bf16* __restrict__ Qb,
    const bf16* __restrict__ Kb, const bf16* __restrict__ Vb,
    bf16* __restrict__ Ob)
{
    __shared__ __align__(16) char KL[4][16384];
    __shared__ __align__(16) char VL[4][16384];

    const int tid  = threadIdx.x;
    const int wave = tid >> 6, lane = tid & 63;
    const int l15 = lane & 15, l4 = lane >> 4;
    // wgid bits: [0:3)=bh_low, [3:6)=qt, [6:8)=bh_high -> all 8 qt of a bh
    // share wgid%8 (same XCD); bijective over 256.
    const int wgid = blockIdx.x;
    const int qt = (wgid >> 3) & 7;
    const int bh = ((wgid >> 6) << 3) | (wgid & 7);
    const int qbase = qt*128 + wave*16;

    bf16x8 qf[4];
    {
        const bf16* qptr = Qb + ((size_t)bh*SS + qbase + l15)*DK;
        #pragma unroll
        for (int ks = 0; ks < 4; ++ks)
            qf[ks] = *(const bf16x8*)(qptr + ks*32 + l4*8);
    }

    const char* kblobs = (const char*)Kb + (((size_t)bh*KVTILES) << 14);
    const char* vblobs = (const char*)Vb + (((size_t)bh*KVTILES) << 14);
    const int soff = wave*2048;

    bf16x8 ones8;
    #pragma unroll
    for (int e = 0; e < 8; ++e) ones8[e] = (bf16)1.0f;

    float m_run = -1e30f;
    f32x4 oacc[8];
    f32x4 lacc;
    #pragma unroll
    for (int df = 0; df < 8; ++df) oacc[df] = f32x4{0.f,0.f,0.f,0.f};
    lacc = f32x4{0.f,0.f,0.f,0.f};

    // prologue: issue tiles 0 and 1
    #pragma unroll
    for (int tt = 0; tt < 2; ++tt)
        #pragma unroll
        for (int c = 0; c < 2; ++c) {
            gload16(kblobs + ((size_t)tt << 14) + soff + c*1024 + lane*16, KL[tt] + soff + c*1024);
            gload16(vblobs + ((size_t)tt << 14) + soff + c*1024 + lane*16, VL[tt] + soff + c*1024);
        }
    const char* kpf = kblobs + (2 << 14);   // next tile to prefetch
    const char* vpf = vblobs + (2 << 14);

#define TILE_STEP(T, BUF)                                                          \
    {                                                                              \
        if ((T) + 2 < NT) {                                                        \
            const int nb = ((BUF) + 2) & 3;                                        \
            _Pragma("unroll")                                                      \
            for (int c = 0; c < 2; ++c) {                                          \
                gload16(kpf + soff + c*1024 + lane*16, KL[nb] + soff + c*1024);    \
                gload16(vpf + soff + c*1024 + lane*16, VL[nb] + soff + c*1024);    \
            }                                                                      \
            kpf += 16384; vpf += 16384;                                            \
            asm volatile("s_waitcnt vmcnt(8)" ::: "memory");                       \
        } else if ((T) + 1 < NT) {                                                 \
            asm volatile("s_waitcnt vmcnt(4)" ::: "memory");                       \
        } else {                                                                   \
            asm volatile("s_waitcnt vmcnt(0)" ::: "memory");                       \
        }                                                                          \
        __builtin_amdgcn_s_barrier();                                              \
        const char* Kc = KL[BUF];                                                  \
        const char* Vc = VL[BUF];                                                  \
        f32x4 sa[4];                                                               \
        _Pragma("unroll")                                                          \
        for (int nf = 0; nf < 4; ++nf) sa[nf] = f32x4{0.f,0.f,0.f,0.f};            \
        __builtin_amdgcn_s_setprio(1);                                             \
        _Pragma("unroll")                                                          \
        for (int nf = 0; nf < 4; ++nf) {                                           \
            const int krow = nf*16 + l15;                                          \
            const int rx = (krow & 7) << 4;                                        \
            _Pragma("unroll")                                                      \
            for (int ks = 0; ks < 4; ++ks) {                                       \
                bf16x8 kf = *(const bf16x8*)(Kc + krow*256 + ((ks*64 + l4*16) ^ rx)); \
                sa[nf] = __builtin_amdgcn_mfma_f32_16x16x32_bf16(kf, qf[ks], sa[nf], 0,0,0); \
            }                                                                      \
        }                                                                          \
        __builtin_amdgcn_s_setprio(0);                                             \
        float a0 = fmaxf(fmaxf(sa[0][0], sa[0][1]), fmaxf(sa[0][2], sa[0][3]));    \
        float a1 = fmaxf(fmaxf(sa[1][0], sa[1][1]), fmaxf(sa[1][2], sa[1][3]));    \
        float a2 = fmaxf(fmaxf(sa[2][0], sa[2][1]), fmaxf(sa[2][2], sa[2][3]));    \
        float a3 = fmaxf(fmaxf(sa[3][0], sa[3][1]), fmaxf(sa[3][2], sa[3][3]));    \
        float mt2 = fmaxf(fmaxf(a0, a1), fmaxf(a2, a3));                           \
        mt2 = fmaxf(mt2, __shfl_xor(mt2, 16, 64));                                 \
        mt2 = fmaxf(mt2, __shfl_xor(mt2, 32, 64));                                 \
        const bool ok = (mt2 <= m_run + 8.0f);                                     \
        if (!__all(ok)) {                                                          \
            const float mn   = fmaxf(m_run, mt2);                                  \
            const float corr = exp2f(m_run - mn);                                  \
            m_run = mn;                                                            \
            _Pragma("unroll")                                                      \
            for (int r = 0; r < 4; ++r) {                                          \
                const float c = __shfl(corr, (lane & 48) | (l4*4 + r), 64);        \
                lacc[r] *= c;                                                      \
                _Pragma("unroll")                                                  \
                for (int df = 0; df < 8; ++df) oacc[df][r] *= c;                   \
            }                                                                      \
        }                                                                          \
        bf16x8 pf[2];                                                              \
        _Pragma("unroll")                                                          \
        for (int ks2 = 0; ks2 < 2; ++ks2) {                                        \
            bf16x8 v;                                                              \
            _Pragma("unroll")                                                      \
            for (int e = 0; e < 8; ++e)                                            \
                v[e] = (bf16)exp2f(sa[ks2*2 + (e >> 2)][e & 3] - m_run);           \
            pf[ks2] = v;                                                           \
        }                                                                          \
        __builtin_amdgcn_s_setprio(1);                                             \
        _Pragma("unroll")                                                          \
        for (int ks2 = 0; ks2 < 2; ++ks2) {                                        \
            lacc = __builtin_amdgcn_mfma_f32_16x16x32_bf16(pf[ks2], ones8, lacc, 0,0,0); \
            _Pragma("unroll")                                                      \
            for (int df = 0; df < 8; ++df) {                                       \
                const int d = df*16 + l15;                                         \
                bf16x8 vf = *(const bf16x8*)(Vc + d*128 + ((ks2*64 + l4*16) ^ ((d&7)<<4))); \
                oacc[df] = __builtin_amdgcn_mfma_f32_16x16x32_bf16(pf[ks2], vf, oacc[df], 0,0,0); \
            }                                                                      \
        }                                                                          \
        __builtin_amdgcn_s_setprio(0);                                             \
    }

    for (int t4 = 0; t4 < NT; t4 += 4) {
        TILE_STEP(t4 + 0, 0)
        TILE_STEP(t4 + 1, 1)
        TILE_STEP(t4 + 2, 2)
        TILE_STEP(t4 + 3, 3)
    }
#undef TILE_STEP

    // ---- epilogue: normalized final O, bf16 [B*S][DMODEL], col = h*128+d ----
    // lacc[r] holds l for q = qbase + l4*4 + r (same row layout as oacc) in
    // every l15 column (B = ones), so normalization needs no shuffles.
    const int b = bh >> 4, h = bh & 15;
    float inv[4];
    #pragma unroll
    for (int r = 0; r < 4; ++r) inv[r] = 1.f / lacc[r];
    #pragma unroll
    for (int df = 0; df < 8; ++df)
        #pragma unroll
        for (int r = 0; r < 4; ++r) {
            const int q = qbase + l4*4 + r;
            Ob[((size_t)(b*SS + q))*DMODEL + h*DK + df*16 + l15] = (bf16)(oacc[df][r]*inv[r]);
        }
}

extern "C" void kernel_launch(void* const* d_in, const int* in_sizes, int n_in,
                              void* d_out, int out_size, void* d_ws, size_t ws_size,
                              hipStream_t stream) {
    const float* x  = (const float*)d_in[0];
    const float* pk = (const float*)d_in[1];
    const float* pv = (const float*)d_in[2];
    const float* Wq = (const float*)d_in[3];
    const float* bq = (const float*)d_in[4];
    const float* Wk = (const float*)d_in[5];
    const float* bk = (const float*)d_in[6];
    const float* Wv = (const float*)d_in[7];
    const float* bv = (const float*)d_in[8];
    const float* Wo = (const float*)d_in[9];
    const float* bo = (const float*)d_in[10];

    float* out  = (float*)d_out;                 // [B,S,DMODEL] (16 MB)
    float* Kout = out + 4194304;                 // [B,H,4096,128] fp32
    float* Vout = out + 20971520;

    char* ws = (char*)d_ws;
    bf16* xb    = (bf16*)(ws);
    bf16* Wqb   = (bf16*)(ws + (size_t)8*1024*1024);
    bf16* Wkb   = (bf16*)(ws + (size_t)16*1024*1024);
    bf16* Wvb   = (bf16*)(ws + (size_t)24*1024*1024);
    bf16* Wob   = (bf16*)(ws + (size_t)32*1024*1024);
    bf16* Qb    = (bf16*)(ws + (size_t)40*1024*1024);
    bf16* Ob    = (bf16*)(ws + (size_t)48*1024*1024);
    bf16* Kb    = (bf16*)(ws + (size_t)56*1024*1024);   // 32 MB swizzled tiles
    bf16* Vb    = (bf16*)(ws + (size_t)88*1024*1024);   // 32 MB swizzled tiles

    // 1) fp32 -> bf16 converts
    cvt5_k<<<dim3(1024, 5), 256, 0, stream>>>(x, Wq, Wk, Wv, Wo,
                                              xb, Wqb, Wkb, Wvb, Wob, 524288);
    // 2) fused QKV projection (writes Qb bf16 + new K/V fp32 rows)
    gemm_bt<<<dim3(16, 48), 256, 0, stream>>>(xb, Wqb, Wkb, Wvb, bq, bk, bv,
                                              Qb, Kout, Vout, nullptr, 0);
    // 3) K/V prep: past fp32 copy + bf16 swizzled tile blobs (all 4096 rows)
    kvprep_k<<<dim3(64, 32), 256, 0, stream>>>(pk, pv, Kout, Vout, Kb, Vb);
    // 4) flash attention (grid 256, no split, writes final O)
    attn_k<<<256, 512, 0, stream>>>(Qb, Kb, Vb, Ob);
    // 5) output projection
    gemm_bt<<<dim3(16, 16), 256, 0, stream>>>(Ob, Wob, nullptr, nullptr, bo, nullptr, nullptr,
                                              nullptr, nullptr, nullptr, out, 1);
}

// Round 16
// 274.153 us; speedup vs baseline: 1.0543x; 1.0543x over previous
//
#include <hip/hip_runtime.h>
#include <stdint.h>

typedef __bf16 bf16;
typedef __bf16 bf16x4 __attribute__((ext_vector_type(4)));
typedef __bf16 bf16x8 __attribute__((ext_vector_type(8)));
typedef float  f32x4  __attribute__((ext_vector_type(4)));

#define DMODEL 2048
#define NH 16
#define DK 128
#define SS 1024
#define PASTLEN 3072
#define LTOT 4096
#define KVTILES 64
#define NSPLIT 2
#define NT 32            // kv tiles per split (64 / NSPLIT)

// ---- async global->LDS, 16B per lane (wave-uniform LDS base + lane*16) ----
__device__ __forceinline__ void gload16(const void* g, void* l) {
    __builtin_amdgcn_global_load_lds(
        (__attribute__((address_space(1))) void*)(uintptr_t)g,
        (__attribute__((address_space(3))) void*)(uintptr_t)l,
        16, 0, 0);
}

// ---- fp32 -> bf16 convert, 5 equal-size tensors selected by blockIdx.y ----
__global__ __launch_bounds__(256) void cvt5_k(
    const float* __restrict__ s0, const float* __restrict__ s1,
    const float* __restrict__ s2, const float* __restrict__ s3,
    const float* __restrict__ s4,
    bf16* __restrict__ d0, bf16* __restrict__ d1, bf16* __restrict__ d2,
    bf16* __restrict__ d3, bf16* __restrict__ d4, int n8)
{
    const float* s; bf16* d;
    switch (blockIdx.y) {
        case 0: s = s0; d = d0; break;
        case 1: s = s1; d = d1; break;
        case 2: s = s2; d = d2; break;
        case 3: s = s3; d = d3; break;
        default: s = s4; d = d4; break;
    }
    int stride = gridDim.x * blockDim.x;
    for (int i = blockIdx.x*blockDim.x + threadIdx.x; i < n8; i += stride) {
        const float4* p = (const float4*)s + (size_t)i*2;
        float4 a = p[0], b = p[1];
        bf16x8 o;
        o[0]=(bf16)a.x; o[1]=(bf16)a.y; o[2]=(bf16)a.z; o[3]=(bf16)a.w;
        o[4]=(bf16)b.x; o[5]=(bf16)b.y; o[6]=(bf16)b.z; o[7]=(bf16)b.w;
        *((bf16x8*)d + i) = o;
    }
}

// ---- Y = A(bf16 MxK) @ W^T + bias ; 128x128 tile, BK=32 (m97 structure) ----
__global__ __launch_bounds__(256) void gemm_bt(
    const bf16* __restrict__ A,
    const bf16* __restrict__ W0, const bf16* __restrict__ W1, const bf16* __restrict__ W2,
    const float* __restrict__ b0, const float* __restrict__ b1, const float* __restrict__ b2,
    bf16* __restrict__ outQ, float* __restrict__ outK, float* __restrict__ outV,
    float* __restrict__ outO, int mode)
{
    __shared__ __align__(16) bf16 As[128*32];
    __shared__ __align__(16) bf16 Bs[128*32];
    const int tid  = threadIdx.x;
    const int wave = tid >> 6, lane = tid & 63;
    const int l15 = lane & 15, l4 = lane >> 4;
    int which, ntile;
    if (mode == 0) { which = blockIdx.y >> 4; ntile = blockIdx.y & 15; }
    else           { which = 3;               ntile = blockIdx.y; }
    const bf16*  W    = (mode != 0 || which == 0) ? W0 : (which == 1 ? W1 : W2);
    const float* bias = (mode != 0 || which == 0) ? b0 : (which == 1 ? b1 : b2);
    const int m0 = blockIdx.x * 128, n0 = ntile * 128;
    const int wm = wave >> 1, wn = wave & 1;

    f32x4 acc[4][4] = {};

    for (int k0 = 0; k0 < DMODEL; k0 += 32) {
        __syncthreads();
        #pragma unroll
        for (int c = 0; c < 2; ++c) {
            const int base = c*4096 + wave*1024;
            const int byte = base + lane*16;
            const int row  = byte >> 6;
            const int ke   = (byte & 63) >> 1;
            gload16(A + (size_t)(m0+row)*DMODEL + k0 + ke, (char*)As + base);
            gload16(W + (size_t)(n0+row)*DMODEL + k0 + ke, (char*)Bs + base);
        }
        asm volatile("s_waitcnt vmcnt(0)" ::: "memory");
        __syncthreads();
        bf16x8 af[4], bfv[4];
        #pragma unroll
        for (int mf = 0; mf < 4; ++mf)
            af[mf] = *(const bf16x8*)((const char*)As + (wm*64 + mf*16 + l15)*64 + l4*16);
        #pragma unroll
        for (int nf = 0; nf < 4; ++nf)
            bfv[nf] = *(const bf16x8*)((const char*)Bs + (wn*64 + nf*16 + l15)*64 + l4*16);
        #pragma unroll
        for (int mf = 0; mf < 4; ++mf)
            #pragma unroll
            for (int nf = 0; nf < 4; ++nf)
                acc[mf][nf] = __builtin_amdgcn_mfma_f32_16x16x32_bf16(af[mf], bfv[nf], acc[mf][nf], 0, 0, 0);
    }

    float bv4[4];
    #pragma unroll
    for (int nf = 0; nf < 4; ++nf) bv4[nf] = bias[n0 + wn*64 + nf*16 + l15];

    const int rbase = m0 + wm*64 + l4*4;
    const int cbase = n0 + wn*64 + l15;

    if (mode == 1) {
        #pragma unroll
        for (int mf = 0; mf < 4; ++mf)
        #pragma unroll
        for (int nf = 0; nf < 4; ++nf) {
            const int col = cbase + nf*16;
            #pragma unroll
            for (int r = 0; r < 4; ++r) {
                const int row = rbase + mf*16 + r;
                outO[(size_t)row*DMODEL + col] = acc[mf][nf][r] + bv4[nf];
            }
        }
    } else if (which == 0) {
        const float qs = 0.08838834764831845f * 1.4426950408889634f;
        #pragma unroll
        for (int mf = 0; mf < 4; ++mf)
        #pragma unroll
        for (int nf = 0; nf < 4; ++nf) {
            const int col = cbase + nf*16;
            const int h = col >> 7, d = col & 127;
            #pragma unroll
            for (int r = 0; r < 4; ++r) {
                const int row = rbase + mf*16 + r;
                const int b = row >> 10, s = row & 1023;
                outQ[((size_t)(b*NH + h)*SS + s)*DK + d] = (bf16)((acc[mf][nf][r] + bv4[nf]) * qs);
            }
        }
    } else {
        float* dst = (which == 1) ? outK : outV;
        #pragma unroll
        for (int mf = 0; mf < 4; ++mf)
        #pragma unroll
        for (int nf = 0; nf < 4; ++nf) {
            const int col = cbase + nf*16;
            const int h = col >> 7, d = col & 127;
            #pragma unroll
            for (int r = 0; r < 4; ++r) {
                const int row = rbase + mf*16 + r;
                const int b = row >> 10, s = row & 1023;
                dst[((size_t)(b*NH + h)*LTOT + PASTLEN + s)*DK + d] = acc[mf][nf][r] + bv4[nf];
            }
        }
    }
}

// ---- K/V prep: past fp32 copy to d_out + bf16 swizzled tile blobs for attn ----
// K blob byte(r,d)  = r*256 + ((d*2) ^ ((r&7)<<4))      [64 rows x 128 d]
// V blob: transposed [d][slot], slot j holds original kv row
//   kv(j) = (j&32) + ((j&4)<<2) + (((j>>3)&3)<<2) + (j&3)
// byte(d, j) = d*128 + ((j*2) ^ ((d&7)<<4))
__global__ __launch_bounds__(256) void kvprep_k(
    const float* __restrict__ pk, const float* __restrict__ pv,
    float* __restrict__ Kf, float* __restrict__ Vf,
    bf16* __restrict__ Kb, bf16* __restrict__ Vb)
{
    __shared__ float Vt_f[64*132];
    const int tid = threadIdx.x;
    const int tau = blockIdx.x, bh = blockIdx.y;
    const bool past = tau < 48;
    const size_t srcoff = past ? ((size_t)bh*PASTLEN + tau*64)*DK
                               : ((size_t)bh*LTOT    + tau*64)*DK;
    const float* srcK = (past ? pk : Kf) + srcoff;
    const float* srcV = (past ? pv : Vf) + srcoff;
    float* dstKf = Kf + ((size_t)bh*LTOT + tau*64)*DK;
    float* dstVf = Vf + ((size_t)bh*LTOT + tau*64)*DK;
    char* kblob = (char*)Kb + (((size_t)bh*KVTILES + tau) << 14);
    char* vblob = (char*)Vb + (((size_t)bh*KVTILES + tau) << 14);

    #pragma unroll
    for (int i = 0; i < 8; ++i) {
        const int f4 = i*256 + tid;
        const int r  = f4 >> 5;
        const int c8 = f4 & 31;
        float4 k4 = ((const float4*)srcK)[f4];
        float4 v4 = ((const float4*)srcV)[f4];
        if (past) {
            ((float4*)dstKf)[f4] = k4;
            ((float4*)dstVf)[f4] = v4;
        }
        bf16x4 kq; kq[0]=(bf16)k4.x; kq[1]=(bf16)k4.y; kq[2]=(bf16)k4.z; kq[3]=(bf16)k4.w;
        *(bf16x4*)(kblob + r*256 + ((c8*8) ^ ((r&7)<<4))) = kq;
        *(float4*)&Vt_f[r*132 + c8*4] = v4;
    }
    __syncthreads();
    const int d = tid >> 1, half = tid & 1;
    const int dx = (d & 7) << 4;
    #pragma unroll
    for (int jj = 0; jj < 4; ++jj) {
        const int chunk = half*4 + jj;     // 16B chunk = slots chunk*8 .. +7
        bf16x8 o;
        #pragma unroll
        for (int e = 0; e < 8; ++e) {
            const int j  = chunk*8 + e;
            const int oe = (j & 32) + ((j & 4) << 2) + (((j >> 3) & 3) << 2) + (j & 3);
            o[e] = (bf16)Vt_f[oe*132 + d];
        }
        *(bf16x8*)(vblob + d*128 + ((chunk*16) ^ dx)) = o;
    }
}

// ---- flash attention v13 (round-14 best): split-KV=2, 8 waves x 32q ----
// depth-4 K/V buffers, static buffer indices, 1 barrier/tile,
// swapped QK^T (S^T), P fully in-register. Grid 256 = 1 block/CU.
__global__ __launch_bounds__(512, 2) void attn_k(
    const bf16* __restrict__ Qb,
    const bf16* __restrict__ Kb, const bf16* __restrict__ Vb,
    bf16* __restrict__ Opart, float* __restrict__ Marr, float* __restrict__ Larr)
{
    __shared__ __align__(16) char KL[4][16384];
    __shared__ __align__(16) char VL[4][16384];

    const int tid  = threadIdx.x;
    const int wave = tid >> 6, lane = tid & 63;
    const int l15 = lane & 15, l4 = lane >> 4;
    // wgid = (g/8)*32 + qt*8 + (g%8), g = bh*2+sp -> all qt share wgid%8 (XCD)
    const int wgid = blockIdx.x;
    const int qt = (wgid >> 3) & 3;
    const int g  = ((wgid >> 5) << 3) | (wgid & 7);
    const int bh = g >> 1, sp = g & 1;
    const int qbase = qt*256 + wave*32;

    bf16x8 qf[2][4];
    #pragma unroll
    for (int qq = 0; qq < 2; ++qq) {
        const bf16* qptr = Qb + ((size_t)bh*SS + qbase + qq*16 + l15)*DK;
        #pragma unroll
        for (int ks = 0; ks < 4; ++ks)
            qf[qq][ks] = *(const bf16x8*)(qptr + ks*32 + l4*8);
    }

    const char* kblobs = (const char*)Kb + (((size_t)bh*KVTILES + sp*NT) << 14);
    const char* vblobs = (const char*)Vb + (((size_t)bh*KVTILES + sp*NT) << 14);
    const int soff = wave*2048;

    bf16x8 ones8;
    #pragma unroll
    for (int e = 0; e < 8; ++e) ones8[e] = (bf16)1.0f;

    float m_run[2];
    f32x4 oacc[2][8];
    f32x4 lacc[2];
    m_run[0] = -1e30f; m_run[1] = -1e30f;
    #pragma unroll
    for (int qq = 0; qq < 2; ++qq) {
        #pragma unroll
        for (int df = 0; df < 8; ++df) oacc[qq][df] = f32x4{0.f,0.f,0.f,0.f};
        lacc[qq] = f32x4{0.f,0.f,0.f,0.f};
    }

    // prologue: issue tiles 0 and 1
    #pragma unroll
    for (int tt = 0; tt < 2; ++tt)
        #pragma unroll
        for (int c = 0; c < 2; ++c) {
            gload16(kblobs + ((size_t)tt << 14) + soff + c*1024 + lane*16, KL[tt] + soff + c*1024);
            gload16(vblobs + ((size_t)tt << 14) + soff + c*1024 + lane*16, VL[tt] + soff + c*1024);
        }
    const char* kpf = kblobs + (2 << 14);   // next tile to prefetch
    const char* vpf = vblobs + (2 << 14);

#define TILE_STEP(T, BUF)                                                          \
    {                                                                              \
        if ((T) + 2 < NT) {                                                        \
            const int nb = ((BUF) + 2) & 3;                                        \
            _Pragma("unroll")                                                      \
            for (int c = 0; c < 2; ++c) {                                          \
                gload16(kpf + soff + c*1024 + lane*16, KL[nb] + soff + c*1024);    \
                gload16(vpf + soff + c*1024 + lane*16, VL[nb] + soff + c*1024);    \
            }                                                                      \
            kpf += 16384; vpf += 16384;                                            \
            asm volatile("s_waitcnt vmcnt(8)" ::: "memory");                       \
        } else if ((T) + 1 < NT) {                                                 \
            asm volatile("s_waitcnt vmcnt(4)" ::: "memory");                       \
        } else {                                                                   \
            asm volatile("s_waitcnt vmcnt(0)" ::: "memory");                       \
        }                                                                          \
        __builtin_amdgcn_s_barrier();                                              \
        const char* Kc = KL[BUF];                                                  \
        const char* Vc = VL[BUF];                                                  \
        f32x4 sa[2][4];                                                            \
        _Pragma("unroll")                                                          \
        for (int qq = 0; qq < 2; ++qq)                                             \
            _Pragma("unroll")                                                      \
            for (int nf = 0; nf < 4; ++nf) sa[qq][nf] = f32x4{0.f,0.f,0.f,0.f};    \
        __builtin_amdgcn_s_setprio(1);                                             \
        _Pragma("unroll")                                                          \
        for (int nf = 0; nf < 4; ++nf) {                                           \
            const int krow = nf*16 + l15;                                          \
            const int rx = (krow & 7) << 4;                                        \
            _Pragma("unroll")                                                      \
            for (int ks = 0; ks < 4; ++ks) {                                       \
                bf16x8 kf = *(const bf16x8*)(Kc + krow*256 + ((ks*64 + l4*16) ^ rx)); \
                sa[0][nf] = __builtin_amdgcn_mfma_f32_16x16x32_bf16(kf, qf[0][ks], sa[0][nf], 0,0,0); \
                sa[1][nf] = __builtin_amdgcn_mfma_f32_16x16x32_bf16(kf, qf[1][ks], sa[1][nf], 0,0,0); \
            }                                                                      \
        }                                                                          \
        __builtin_amdgcn_s_setprio(0);                                             \
        float mt2[2];                                                              \
        _Pragma("unroll")                                                          \
        for (int qq = 0; qq < 2; ++qq) {                                           \
            float a0 = fmaxf(fmaxf(sa[qq][0][0], sa[qq][0][1]), fmaxf(sa[qq][0][2], sa[qq][0][3])); \
            float a1 = fmaxf(fmaxf(sa[qq][1][0], sa[qq][1][1]), fmaxf(sa[qq][1][2], sa[qq][1][3])); \
            float a2 = fmaxf(fmaxf(sa[qq][2][0], sa[qq][2][1]), fmaxf(sa[qq][2][2], sa[qq][2][3])); \
            float a3 = fmaxf(fmaxf(sa[qq][3][0], sa[qq][3][1]), fmaxf(sa[qq][3][2], sa[qq][3][3])); \
            float v = fmaxf(fmaxf(a0, a1), fmaxf(a2, a3));                         \
            v = fmaxf(v, __shfl_xor(v, 16, 64));                                   \
            v = fmaxf(v, __shfl_xor(v, 32, 64));                                   \
            mt2[qq] = v;                                                           \
        }                                                                          \
        const bool ok = (mt2[0] <= m_run[0] + 8.0f) && (mt2[1] <= m_run[1] + 8.0f); \
        if (!__all(ok)) {                                                          \
            _Pragma("unroll")                                                      \
            for (int qq = 0; qq < 2; ++qq) {                                       \
                const float mn   = fmaxf(m_run[qq], mt2[qq]);                      \
                const float corr = exp2f(m_run[qq] - mn);                          \
                m_run[qq] = mn;                                                    \
                _Pragma("unroll")                                                  \
                for (int r = 0; r < 4; ++r) {                                      \
                    const float c = __shfl(corr, (lane & 48) | (l4*4 + r), 64);    \
                    lacc[qq][r] *= c;                                              \
                    _Pragma("unroll")                                              \
                    for (int df = 0; df < 8; ++df) oacc[qq][df][r] *= c;           \
                }                                                                  \
            }                                                                      \
        }                                                                          \
        bf16x8 pf[2][2];                                                           \
        _Pragma("unroll")                                                          \
        for (int qq = 0; qq < 2; ++qq)                                             \
            _Pragma("unroll")                                                      \
            for (int ks2 = 0; ks2 < 2; ++ks2) {                                    \
                bf16x8 v;                                                          \
                _Pragma("unroll")                                                  \
                for (int e = 0; e < 8; ++e)                                        \
                    v[e] = (bf16)exp2f(sa[qq][ks2*2 + (e >> 2)][e & 3] - m_run[qq]); \
                pf[qq][ks2] = v;                                                   \
            }                                                                      \
        __builtin_amdgcn_s_setprio(1);                                             \
        _Pragma("unroll")                                                          \
        for (int ks2 = 0; ks2 < 2; ++ks2) {                                        \
            lacc[0] = __builtin_amdgcn_mfma_f32_16x16x32_bf16(pf[0][ks2], ones8, lacc[0], 0,0,0); \
            lacc[1] = __builtin_amdgcn_mfma_f32_16x16x32_bf16(pf[1][ks2], ones8, lacc[1], 0,0,0); \
            _Pragma("unroll")                                                      \
            for (int df = 0; df < 8; ++df) {                                       \
                const int d = df*16 + l15;                                         \
                bf16x8 vf = *(const bf16x8*)(Vc + d*128 + ((ks2*64 + l4*16) ^ ((d&7)<<4))); \
                oacc[0][df] = __builtin_amdgcn_mfma_f32_16x16x32_bf16(pf[0][ks2], vf, oacc[0][df], 0,0,0); \
                oacc[1][df] = __builtin_amdgcn_mfma_f32_16x16x32_bf16(pf[1][ks2], vf, oacc[1][df], 0,0,0); \
            }                                                                      \
        }                                                                          \
        __builtin_amdgcn_s_setprio(0);                                             \
    }

    for (int t4 = 0; t4 < NT; t4 += 4) {
        TILE_STEP(t4 + 0, 0)
        TILE_STEP(t4 + 1, 1)
        TILE_STEP(t4 + 2, 2)
        TILE_STEP(t4 + 3, 3)
    }
#undef TILE_STEP

    // ---- epilogue: unnormalized partial O (bf16) + per-row m,l ----
    bf16* op = Opart + ((size_t)sp*32 + bh)*SS*DK;
    #pragma unroll
    for (int qq = 0; qq < 2; ++qq)
        #pragma unroll
        for (int df = 0; df < 8; ++df)
            #pragma unroll
            for (int r = 0; r < 4; ++r) {
                const int q = qbase + qq*16 + l4*4 + r;
                op[(size_t)q*DK + df*16 + l15] = (bf16)oacc[qq][df][r];
            }
    if (l4 == 0) {
        #pragma unroll
        for (int qq = 0; qq < 2; ++qq)
            Marr[(size_t)sp*32768 + bh*SS + qbase + qq*16 + l15] = m_run[qq];
    }
    if (l15 == 0) {
        #pragma unroll
        for (int qq = 0; qq < 2; ++qq)
            #pragma unroll
            for (int r = 0; r < 4; ++r) {
                const int q = qbase + qq*16 + l4*4 + r;
                Larr[(size_t)sp*32768 + bh*SS + q] = lacc[qq][r];
            }
    }
}

// ---- combine the two KV splits -> Ob bf16 [B*S][DMODEL] ----
__global__ __launch_bounds__(256) void combine_k(
    const bf16* __restrict__ Opart, const float* __restrict__ Marr,
    const float* __restrict__ Larr, bf16* __restrict__ Ob)
{
    const int gid = blockIdx.x*256 + threadIdx.x;   // 32768 rows x 16 chunks
    const int row = gid >> 4;
    const int c8  = gid & 15;
    const int bh = row >> 10, q = row & 1023;
    float m[NSPLIT], l[NSPLIT];
    #pragma unroll
    for (int s = 0; s < NSPLIT; ++s) {
        m[s] = Marr[(size_t)s*32768 + row];
        l[s] = Larr[(size_t)s*32768 + row];
    }
    float M = m[0];
    #pragma unroll
    for (int s = 1; s < NSPLIT; ++s) M = fmaxf(M, m[s]);
    float w[NSPLIT], den = 0.f;
    #pragma unroll
    for (int s = 0; s < NSPLIT; ++s) { w[s] = exp2f(m[s] - M); den += l[s]*w[s]; }
    const float inv = 1.f / den;
    #pragma unroll
    for (int s = 0; s < NSPLIT; ++s) w[s] *= inv;
    float acc[8] = {};
    #pragma unroll
    for (int s = 0; s < NSPLIT; ++s) {
        bf16x8 p = *(const bf16x8*)(Opart + (size_t)s*4194304 + (size_t)row*DK + c8*8);
        #pragma unroll
        for (int e = 0; e < 8; ++e) acc[e] += (float)p[e]*w[s];
    }
    const int b = bh >> 4, h = bh & 15;
    bf16x8 o;
    #pragma unroll
    for (int e = 0; e < 8; ++e) o[e] = (bf16)acc[e];
    *(bf16x8*)(Ob + ((size_t)(b*SS + q))*DMODEL + h*DK + c8*8) = o;
}

extern "C" void kernel_launch(void* const* d_in, const int* in_sizes, int n_in,
                              void* d_out, int out_size, void* d_ws, size_t ws_size,
                              hipStream_t stream) {
    const float* x  = (const float*)d_in[0];
    const float* pk = (const float*)d_in[1];
    const float* pv = (const float*)d_in[2];
    const float* Wq = (const float*)d_in[3];
    const float* bq = (const float*)d_in[4];
    const float* Wk = (const float*)d_in[5];
    const float* bk = (const float*)d_in[6];
    const float* Wv = (const float*)d_in[7];
    const float* bv = (const float*)d_in[8];
    const float* Wo = (const float*)d_in[9];
    const float* bo = (const float*)d_in[10];

    float* out  = (float*)d_out;                 // [B,S,DMODEL] (16 MB)
    float* Kout = out + 4194304;                 // [B,H,4096,128] fp32
    float* Vout = out + 20971520;

    char* ws = (char*)d_ws;
    bf16* xb    = (bf16*)(ws);
    bf16* Wqb   = (bf16*)(ws + (size_t)8*1024*1024);
    bf16* Wkb   = (bf16*)(ws + (size_t)16*1024*1024);
    bf16* Wvb   = (bf16*)(ws + (size_t)24*1024*1024);
    bf16* Wob   = (bf16*)(ws + (size_t)32*1024*1024);
    bf16* Qb    = (bf16*)(ws + (size_t)40*1024*1024);
    bf16* Ob    = (bf16*)(ws + (size_t)48*1024*1024);
    bf16* Kb    = (bf16*)(ws + (size_t)56*1024*1024);   // 32 MB swizzled tiles
    bf16* Vb    = (bf16*)(ws + (size_t)88*1024*1024);   // 32 MB swizzled tiles
    // recycled after QKV GEMM (xb/Wqb/Wkb/Wvb dead): Opart = 2 splits x 8 MB
    bf16*  Opart = (bf16*)(ws);
    // M/L live in the d_out "out" region (free until final GEMM overwrites it)
    float* Marr  = out;                 // 2*32768 floats
    float* Larr  = out + 131072;

    // 1) fp32 -> bf16 converts
    cvt5_k<<<dim3(2048, 5), 256, 0, stream>>>(x, Wq, Wk, Wv, Wo,
                                              xb, Wqb, Wkb, Wvb, Wob, 524288);
    // 2) fused QKV projection (writes Qb bf16 + new K/V fp32 rows)
    gemm_bt<<<dim3(16, 48), 256, 0, stream>>>(xb, Wqb, Wkb, Wvb, bq, bk, bv,
                                              Qb, Kout, Vout, nullptr, 0);
    // 3) K/V prep: past fp32 copy + bf16 swizzled tile blobs (all 4096 rows)
    kvprep_k<<<dim3(64, 32), 256, 0, stream>>>(pk, pv, Kout, Vout, Kb, Vb);
    // 4) flash attention (256 blocks, split-KV=2, XCD-bijective swizzle, depth-4)
    attn_k<<<256, 512, 0, stream>>>(Qb, Kb, Vb, Opart, Marr, Larr);
    // 5) combine splits
    combine_k<<<2048, 256, 0, stream>>>(Opart, Marr, Larr, Ob);
    // 6) output projection
    gemm_bt<<<dim3(16, 16), 256, 0, stream>>>(Ob, Wob, nullptr, nullptr, bo, nullptr, nullptr,
                                              nullptr, nullptr, nullptr, out, 1);
}